// Round 5
// baseline (394.364 us; speedup 1.0000x reference)
//
#include <hip/hip_runtime.h>
#include <hip/hip_bf16.h>
#include <cfloat>

// VecPointNet on MI355X, round 5:
//  - GEMM: 512 blocks (2/CU), 8 waves each owning one 16-row fragment (halved
//    per-wave critical path, doubled occupancy), __launch_bounds__(512,4).
//  - yg partial reduction fused into gemm<0> epilogue (shfl_xor over col group).
//  - yg stage2 + bias merged into one 1-block kernel.
//  - knn/edge/pack unchanged from round 4.

typedef __attribute__((ext_vector_type(8))) short short8;
typedef __attribute__((ext_vector_type(4))) float f32x4;

__device__ __forceinline__ unsigned short f2bf(float f) {
    union { float f; unsigned u; } v; v.f = f;
    unsigned r = v.u + 0x7fffu + ((v.u >> 16) & 1u);
    return (unsigned short)(r >> 16);
}
__device__ __forceinline__ float bf2f(unsigned short h) {
    union { unsigned u; float f; } v; v.u = ((unsigned)h) << 16;
    return v.f;
}

// ---------------- prep: pts4[b][n] = (x,y,z, x^2+y^2+z^2) ----------------
__global__ __launch_bounds__(256) void prep_kernel(const float* __restrict__ x,
                                                   float4* __restrict__ pts4,
                                                   int N, int B) {
    int t = blockIdx.x * 256 + threadIdx.x;
    if (t >= B * N) return;
    int b = t / N, n = t - b * N;
    const float* xb = x + (long)b * 3 * N;
    float px = xb[n], py = xb[N + n], pz = xb[2 * N + n];
    float sq = px * px + py * py + pz * pz;
    pts4[t] = make_float4(px, py, pz, sq);
}

// ---------------- knn: one wave per query, ballot-filtered top-16 ----------------
__global__ __launch_bounds__(1024) void knn_kernel(const float4* __restrict__ pts4,
                                                   int* __restrict__ idxOut, int N) {
    __shared__ float4 cbuf[4096];   // 64 KB
    int t = threadIdx.x;
    int tilesPerB = N / 16;
    int b = blockIdx.x / tilesPerB;
    int q = (blockIdx.x % tilesPerB) * 16 + (t >> 6);
    int lane = t & 63;

    for (int i = t; i < N; i += 1024) cbuf[i] = pts4[b * N + i];
    __syncthreads();

    float4 Q = cbuf[q];
    double k = 1e300;     // lanes 0..15: sorted ascending top-16 keys
    double T = 1e300;     // current 16th-best key (uniform)

    for (int c0 = 0; c0 < N; c0 += 64) {
        float4 C = cbuf[c0 + lane];
        float dot = Q.x * C.x + Q.y * C.y + Q.z * C.z;
        float d2 = Q.w + C.w - 2.0f * dot;          // same formula as reference
        unsigned u = __float_as_uint(d2);
        u ^= (unsigned)((int)u >> 31) | 0x80000000u; // orderable uint
        double key = (double)u * 4096.0 + (double)(c0 + lane);
        unsigned long long mask = __ballot(key < T);
        while (mask) {
            int src = __ffsll(mask) - 1;
            mask &= mask - 1;
            double vb = __shfl(key, src);
            if (vb < T) {                            // uniform branch (stale-mask recheck)
                double km1 = __shfl_up(k, 1);
                if (lane == 0) km1 = -1.0;
                double kn = (vb <= km1) ? km1 : ((vb < k) ? vb : k);
                if (lane < 16) k = kn;
                T = __shfl(k, 15);
            }
        }
    }
    if (lane < 16) {
        long long kl = (long long)k;                 // exact (key < 2^44)
        idxOut[(b * N + q) * 16 + lane] = (int)(kl & 4095);
    }
}

// ---------------- edge features + input LNA + mean over K -> Ytr bf16 hi/lo ----------------
__global__ __launch_bounds__(256) void edge_kernel(const float4* __restrict__ pts4,
                                                   const int* __restrict__ idx,
                                                   const float* __restrict__ Win,
                                                   const float* __restrict__ Uin,
                                                   unsigned short* __restrict__ Yh,
                                                   unsigned short* __restrict__ Yl,
                                                   int N) {
    __shared__ float4 nbuf[8][16];
    __shared__ float4 cpt[8];
    int nTiles = N / 8;
    int b = blockIdx.x / nTiles;
    int n0 = (blockIdx.x % nTiles) * 8;
    int t = threadIdx.x;
    if (t < 128) {
        int pl = t >> 4, k = t & 15;
        int nb = idx[(b * N + n0 + pl) * 16 + k];
        nbuf[pl][k] = pts4[b * N + nb];
    } else if (t < 136) {
        cpt[t - 128] = pts4[b * N + n0 + (t - 128)];
    }
    __syncthreads();
    int o = t & 127, h = t >> 7;
    float w0 = Win[o * 3], w1 = Win[o * 3 + 1], w2 = Win[o * 3 + 2];
    float u0 = Uin[o * 3], u1 = Uin[o * 3 + 1], u2 = Uin[o * 3 + 2];
    for (int pl = h * 4; pl < h * 4 + 4; ++pl) {
        float4 c4 = cpt[pl];
        float inv = 1.0f / fmaxf(sqrtf(c4.w), 1e-12f);
        float ax = c4.x * inv, ay = c4.y * inv, az = c4.z * inv;
        float a0 = 0.f, a1 = 0.f, a2 = 0.f;
        for (int k = 0; k < 16; ++k) {
            float4 nb = nbuf[pl][k];
            float cr0 = ay * nb.z - az * nb.y;
            float cr1 = az * nb.x - ax * nb.z;
            float cr2 = ax * nb.y - ay * nb.x;
            float df0 = nb.x - c4.x, df1 = nb.y - c4.y, df2 = nb.z - c4.z;
            float P0 = w0 * cr0 + w1 * df0 + w2 * c4.x;
            float P1 = w0 * cr1 + w1 * df1 + w2 * c4.y;
            float P2 = w0 * cr2 + w1 * df2 + w2 * c4.z;
            float D0 = u0 * cr0 + u1 * df0 + u2 * c4.x;
            float D1 = u0 * cr1 + u1 * df1 + u2 * c4.y;
            float D2 = u0 * cr2 + u1 * df2 + u2 * c4.z;
            float dot = P0 * D0 + P1 * D1 + P2 * D2;
            float dsq = D0 * D0 + D1 * D1 + D2 * D2;
            if (dot < 0.0f) {
                float s = dot / (dsq + 1e-6f);
                P0 -= s * D0; P1 -= s * D1; P2 -= s * D2;
            }
            a0 += P0; a1 += P1; a2 += P2;
        }
        float vals[3] = { a0 * (1.0f / 16.0f), a1 * (1.0f / 16.0f), a2 * (1.0f / 16.0f) };
        long n = n0 + pl;
#pragma unroll
        for (int c = 0; c < 3; ++c) {
            long off = ((long)(b * 3 + c) * 4096 + n) * 128 + o;
            unsigned short hh = f2bf(vals[c]);
            Yh[off] = hh;
            Yl[off] = f2bf(vals[c] - bf2f(hh));
        }
    }
}

// ---------------- weight pack: per-lane MFMA fragment order, hi/lo ----------------
__global__ __launch_bounds__(256) void pack_kernel(const float* __restrict__ Wl,
                                                   const float* __restrict__ Ul,
                                                   const float* __restrict__ Wg,
                                                   const float* __restrict__ Ug,
                                                   const float* __restrict__ Wout,
                                                   unsigned short* __restrict__ Ah,
                                                   unsigned short* __restrict__ Al) {
    int t = blockIdx.x * 256 + threadIdx.x;     // 0..327679
    int g, r, M; long base;
    if (t < 262144) { g = t >> 15; r = t & 32767; M = 256; base = (long)g << 15; }
    else { int t2 = t - 262144; g = 8 + (t2 >> 14); r = t2 & 16383; M = 128;
           base = 262144 + (long)(g - 8) * 16384; }
    int MF = M >> 4;
    int ks = r / (MF * 512);
    int mf = (r >> 9) % MF;
    int lane = (r >> 3) & 63;
    int j = r & 7;
    int m = mf * 16 + (lane & 15);
    int k = ks * 32 + ((lane >> 4) << 3) + j;
    const float* src; int ldw; int row;
    if (g < 4) {
        ldw = 128; row = m & 127;
        src = (m < 128) ? (Wl + (long)g * 128 * 128) : (Ul + (long)g * 128 * 128);
    } else if (g < 8) {
        ldw = 256; row = m & 127;
        int l = g - 4;
        src = (m < 128) ? (Wg + (long)l * 128 * 256) : (Ug + (long)l * 128 * 256);
    } else {
        ldw = 512; row = m;
        src = Wout + (g - 8) * 128;
    }
    float v = src[(long)row * ldw + k];
    unsigned short h = f2bf(v);
    Ah[base + r] = h;
    Al[base + r] = f2bf(v - bf2f(h));
}

// ---------------- MFMA GEMM, bf16x3, fragments direct from global ----------------
// MODE 0: LNA, no bias; emits per-tile yg partials (shfl_xor col-reduce).
// MODE 1: LNA + bias + fused Wout GEMM (y2 staged in LDS, partial -> Ofp).
// Grid: 512 blocks (b*256 + tile16), 512 threads (8 waves, wave w owns
// P rows 16w..16w+15 via mf=w and D rows via mf=w+8).
template<int MODE>
__global__ __launch_bounds__(512, 4) void gemm_kernel(
    const unsigned short* __restrict__ Aph, const unsigned short* __restrict__ Apl,
    long aOff, long aOffOut,
    const unsigned short* __restrict__ Bh, const unsigned short* __restrict__ Bl,
    const float* __restrict__ biasP, const float* __restrict__ biasD,
    unsigned short* __restrict__ Oh, unsigned short* __restrict__ Ol,
    float* __restrict__ Ofp, float* __restrict__ part, int accum)
{
    const int N = 4096;
    // y2 staging for fused Wout: [c][hi/lo][ ((k>>3)*16 + col)*8 + (k&7) ]
    __shared__ unsigned short ylds[MODE == 1 ? 3 : 1][2][2048];
    int t = threadIdx.x;
    int lane = t & 63, w = t >> 6;
    int b = blockIdx.x >> 8;
    int tile = blockIdx.x & 255;
    int ncol = tile * 16 + (lane & 15);
    int kq = (lane >> 4) << 3;

    f32x4 accP[3] = {};
    f32x4 accD[3] = {};

    const unsigned short* AhB = Aph + aOff;
    const unsigned short* AlB = Apl + aOff;

#pragma unroll
    for (int ks = 0; ks < 4; ++ks) {
        short8 bh[3], bl[3];
#pragma unroll
        for (int c = 0; c < 3; ++c) {
            long boff = ((long)(b * 3 + c) * N + ncol) * 128 + ks * 32 + kq;
            bh[c] = *(const short8*)(Bh + boff);
            bl[c] = *(const short8*)(Bl + boff);
        }
        long aoffP = (((long)ks * 16 + w) * 64 + lane) * 8;
        short8 ahP = *(const short8*)(AhB + aoffP);
        short8 alP = *(const short8*)(AlB + aoffP);
#pragma unroll
        for (int c = 0; c < 3; ++c) {
            accP[c] = __builtin_amdgcn_mfma_f32_16x16x32_bf16(ahP, bh[c], accP[c], 0, 0, 0);
            accP[c] = __builtin_amdgcn_mfma_f32_16x16x32_bf16(ahP, bl[c], accP[c], 0, 0, 0);
            accP[c] = __builtin_amdgcn_mfma_f32_16x16x32_bf16(alP, bh[c], accP[c], 0, 0, 0);
        }
        long aoffD = (((long)ks * 16 + 8 + w) * 64 + lane) * 8;
        short8 ahD = *(const short8*)(AhB + aoffD);
        short8 alD = *(const short8*)(AlB + aoffD);
#pragma unroll
        for (int c = 0; c < 3; ++c) {
            accD[c] = __builtin_amdgcn_mfma_f32_16x16x32_bf16(ahD, bh[c], accD[c], 0, 0, 0);
            accD[c] = __builtin_amdgcn_mfma_f32_16x16x32_bf16(ahD, bl[c], accD[c], 0, 0, 0);
            accD[c] = __builtin_amdgcn_mfma_f32_16x16x32_bf16(alD, bh[c], accD[c], 0, 0, 0);
        }
    }

    int obase = 16 * w + ((lane >> 4) << 2);     // first of 4 output rows
    float Pv[3][4];
#pragma unroll
    for (int r = 0; r < 4; ++r) {
        int o = obase + r;
        float P[3], D[3];
#pragma unroll
        for (int c = 0; c < 3; ++c) {
            P[c] = accP[c][r];
            D[c] = accD[c][r];
            if (MODE == 1) {
                long bb = ((long)(b * 128 + o)) * 3 + c;
                P[c] += biasP[bb];
                D[c] += biasD[bb];
            }
        }
        float dot = P[0] * D[0] + P[1] * D[1] + P[2] * D[2];
        float dsq = D[0] * D[0] + D[1] * D[1] + D[2] * D[2];
        if (dot < 0.0f) {
            float s = dot / (dsq + 1e-6f);
            P[0] -= s * D[0]; P[1] -= s * D[1]; P[2] -= s * D[2];
        }
        Pv[0][r] = P[0]; Pv[1][r] = P[1]; Pv[2][r] = P[2];
    }

#pragma unroll
    for (int c = 0; c < 3; ++c) {
        unsigned short hs[4], ls[4];
#pragma unroll
        for (int r = 0; r < 4; ++r) {
            hs[r] = f2bf(Pv[c][r]);
            ls[r] = f2bf(Pv[c][r] - bf2f(hs[r]));
        }
        long ooff = ((long)(b * 3 + c) * N + ncol) * 128 + obase;
        *(ushort4*)(Oh + ooff) = make_ushort4(hs[0], hs[1], hs[2], hs[3]);
        *(ushort4*)(Ol + ooff) = make_ushort4(ls[0], ls[1], ls[2], ls[3]);
        if (MODE == 1) {
            int li = ((obase >> 3) << 7) + ((lane & 15) << 3) + (obase & 7);
            *(ushort4*)&ylds[c][0][li] = make_ushort4(hs[0], hs[1], hs[2], hs[3]);
            *(ushort4*)&ylds[c][1][li] = make_ushort4(ls[0], ls[1], ls[2], ls[3]);
        }
    }

    if (MODE == 0) {
        // yg partials: sum over the 16 columns of this tile (lanes with same lane>>4)
#pragma unroll
        for (int c = 0; c < 3; ++c) {
#pragma unroll
            for (int r = 0; r < 4; ++r) {
                float v = Pv[c][r];
                v += __shfl_xor(v, 1);
                v += __shfl_xor(v, 2);
                v += __shfl_xor(v, 4);
                v += __shfl_xor(v, 8);
                if ((lane & 15) == 0)
                    part[((long)(b * 3 + c) * 256 + tile) * 128 + (obase + r)] = v;
            }
        }
    }

    if (MODE == 1) {
        __syncthreads();
        f32x4 accO[3] = {};
        const unsigned short* AoH = Aph + aOffOut;
        const unsigned short* AoL = Apl + aOffOut;
#pragma unroll
        for (int ks = 0; ks < 4; ++ks) {
            short8 yh[3], yl[3];
            int li = (((ks << 2) + (lane >> 4)) << 7) + ((lane & 15) << 3);
#pragma unroll
            for (int c = 0; c < 3; ++c) {
                yh[c] = *(const short8*)&ylds[c][0][li];
                yl[c] = *(const short8*)&ylds[c][1][li];
            }
            long aoff = (((long)ks * 8 + w) * 64 + lane) * 8;
            short8 ah = *(const short8*)(AoH + aoff);
            short8 al = *(const short8*)(AoL + aoff);
#pragma unroll
            for (int c = 0; c < 3; ++c) {
                accO[c] = __builtin_amdgcn_mfma_f32_16x16x32_bf16(ah, yh[c], accO[c], 0, 0, 0);
                accO[c] = __builtin_amdgcn_mfma_f32_16x16x32_bf16(ah, yl[c], accO[c], 0, 0, 0);
                accO[c] = __builtin_amdgcn_mfma_f32_16x16x32_bf16(al, yh[c], accO[c], 0, 0, 0);
            }
        }
#pragma unroll
        for (int r = 0; r < 4; ++r) {
            int o = obase + r;
#pragma unroll
            for (int c = 0; c < 3; ++c) {
                long off = ((long)(b * 128 + o) * 3 + c) * N + ncol;
                float v = accO[c][r];
                if (accum) v += Ofp[off];
                Ofp[off] = v;
            }
        }
    }
}

// ---------------- yg stage2 + bias, single block ----------------
// part: [bc][tile 0..255][o 0..127]; bias layout t = (b*128+o)*3+c.
__global__ __launch_bounds__(768) void ygbias_kernel(const float* __restrict__ part,
                                                     const float* __restrict__ Wg,
                                                     const float* __restrict__ Ug,
                                                     float* __restrict__ biasP,
                                                     float* __restrict__ biasD) {
    __shared__ float ygl[768];    // [(b*128+i)*3+c]
    int t = threadIdx.x;          // 0..767
    int bc = t >> 7, o = t & 127;
    float s = 0.f;
    for (int seg = 0; seg < 256; ++seg)
        s += part[((long)bc * 256 + seg) * 128 + o];
    int b = bc / 3, c = bc % 3;
    ygl[(b * 128 + o) * 3 + c] = s * (1.0f / 4096.0f);
    __syncthreads();
    int c2 = t % 3, o2 = (t / 3) % 128, b2 = t / 384;
    float sp = 0.f, sd = 0.f;
    const float* wrow = Wg + o2 * 256 + 128;
    const float* urow = Ug + o2 * 256 + 128;
    for (int i = 0; i < 128; ++i) {
        float y = ygl[(b2 * 128 + i) * 3 + c2];
        sp = fmaf(wrow[i], y, sp);
        sd = fmaf(urow[i], y, sd);
    }
    biasP[t] = sp;
    biasD[t] = sd;
}

// ---------------- mean over N per (b, o, c) row of fp32 out1 ----------------
__global__ __launch_bounds__(256) void reduce_mean_kernel(const float* __restrict__ src, long bs,
                                                          float* __restrict__ dst, int N) {
    __shared__ float red[256];
    int row = blockIdx.x;          // (b*128+o)*3 + c
    int b = row / 384; int rr = row % 384;
    const float* p = src + (long)b * bs + (long)rr * N;
    float s = 0.f;
    for (int i = threadIdx.x; i < N; i += 256) s += p[i];
    red[threadIdx.x] = s;
    __syncthreads();
    for (int st = 128; st > 0; st >>= 1) {
        if (threadIdx.x < st) red[threadIdx.x] += red[threadIdx.x + st];
        __syncthreads();
    }
    if (threadIdx.x == 0) dst[row] = red[0] / (float)N;
}

extern "C" void kernel_launch(void* const* d_in, const int* in_sizes, int n_in,
                              void* d_out, int out_size, void* d_ws, size_t ws_size,
                              hipStream_t stream) {
    const float* x    = (const float*)d_in[0];
    const float* Win  = (const float*)d_in[1];
    const float* Uin  = (const float*)d_in[2];
    const float* Wl   = (const float*)d_in[3];
    const float* Ul   = (const float*)d_in[4];
    const float* Wg   = (const float*)d_in[5];
    const float* Ug   = (const float*)d_in[6];
    const float* Wout = (const float*)d_in[7];

    const int B = 2, N = 4096, H = 128;
    float* out0 = (float*)d_out;                 // (B,128,3) mean
    float* out1 = out0 + (long)B * H * 3;        // (B,128,3,N) fp32

    float* ws = (float*)d_ws;
    long off = 0;
    float4* pts4 = (float4*)ws;                  off += (long)B * N * 4;
    int* idx = (int*)(ws + off);                 off += (long)B * N * 16;
    const long ACT = (long)B * 3 * N * H;        // ushort count
    unsigned short* f0h = (unsigned short*)(ws + off);  off += ACT / 2;
    unsigned short* f0l = (unsigned short*)(ws + off);  off += ACT / 2;
    unsigned short* y1h = (unsigned short*)(ws + off);  off += ACT / 2;
    unsigned short* y1l = (unsigned short*)(ws + off);  off += ACT / 2;
    unsigned short* Aph = (unsigned short*)(ws + off);  off += 327680 / 2;
    unsigned short* Apl = (unsigned short*)(ws + off);  off += 327680 / 2;
    float* part  = ws + off;                     off += 6L * 256 * 128;
    float* biasP = ws + off;                     off += B * H * 3;
    float* biasD = ws + off;                     off += B * H * 3;
    // ~27.6 MB of workspace

    long bs128 = (long)H * 3 * N;

    prep_kernel<<<(B * N + 255) / 256, 256, 0, stream>>>(x, pts4, N, B);
    knn_kernel<<<B * (N / 16), 1024, 0, stream>>>(pts4, idx, N);
    edge_kernel<<<B * (N / 8), 256, 0, stream>>>(pts4, idx, Win, Uin, f0h, f0l, N);
    pack_kernel<<<1280, 256, 0, stream>>>(Wl, Ul, Wg, Ug, Wout, Aph, Apl);

    for (int l = 0; l < 4; ++l) {
        // y1 = LNA(Wl y2prev, Ul y2prev); emits per-tile yg partials
        gemm_kernel<0><<<512, 512, 0, stream>>>(
            Aph, Apl, (long)l * 32768, 0, f0h, f0l, nullptr, nullptr,
            y1h, y1l, nullptr, part, 0);
        // yg = mean(part); bias = Wg[:,128:] @ yg (and Ug)
        ygbias_kernel<<<1, 768, 0, stream>>>(part,
            Wg + (long)l * H * 256, Ug + (long)l * H * 256, biasP, biasD);
        // y2 = LNA(Wg y1 + biasP, Ug y1 + biasD) -> f0 ; out1 (+)= Wout_l @ y2 (fused)
        gemm_kernel<1><<<512, 512, 0, stream>>>(
            Aph, Apl, (long)(4 + l) * 32768, 262144 + (long)l * 16384,
            y1h, y1l, biasP, biasD, f0h, f0l, out1, nullptr, l > 0 ? 1 : 0);
    }
    reduce_mean_kernel<<<B * H * 3, 256, 0, stream>>>(out1, bs128, out0, N);
}

// Round 6
// 374.812 us; speedup vs baseline: 1.0522x; 1.0522x over previous
//
#include <hip/hip_runtime.h>
#include <hip/hip_bf16.h>
#include <cfloat>

// VecPointNet on MI355X, round 6:
//  - GEMM reverted to the r4 structure (256 blocks, 512 thr, (512,1), pi-loop)
//    -- r5's (512,4) VGPR cap caused spills and +39us.
//  - Kept from r5: yg partials fused into gemm<0> epilogue + single ygbias kernel.
//  - kNN: scan loop unrolled x2 (independent load/compute chains, sequential
//    ballots; insertion is order-independent so semantics unchanged).

typedef __attribute__((ext_vector_type(8))) short short8;
typedef __attribute__((ext_vector_type(4))) float f32x4;

__device__ __forceinline__ unsigned short f2bf(float f) {
    union { float f; unsigned u; } v; v.f = f;
    unsigned r = v.u + 0x7fffu + ((v.u >> 16) & 1u);
    return (unsigned short)(r >> 16);
}
__device__ __forceinline__ float bf2f(unsigned short h) {
    union { unsigned u; float f; } v; v.u = ((unsigned)h) << 16;
    return v.f;
}

// ---------------- prep: pts4[b][n] = (x,y,z, x^2+y^2+z^2) ----------------
__global__ __launch_bounds__(256) void prep_kernel(const float* __restrict__ x,
                                                   float4* __restrict__ pts4,
                                                   int N, int B) {
    int t = blockIdx.x * 256 + threadIdx.x;
    if (t >= B * N) return;
    int b = t / N, n = t - b * N;
    const float* xb = x + (long)b * 3 * N;
    float px = xb[n], py = xb[N + n], pz = xb[2 * N + n];
    float sq = px * px + py * py + pz * pz;
    pts4[t] = make_float4(px, py, pz, sq);
}

// ---------------- knn: one wave per query, ballot-filtered top-16, unroll x2 ----------------
__global__ __launch_bounds__(1024) void knn_kernel(const float4* __restrict__ pts4,
                                                   int* __restrict__ idxOut, int N) {
    __shared__ float4 cbuf[4096];   // 64 KB
    int t = threadIdx.x;
    int tilesPerB = N / 16;
    int b = blockIdx.x / tilesPerB;
    int q = (blockIdx.x % tilesPerB) * 16 + (t >> 6);
    int lane = t & 63;

    for (int i = t; i < N; i += 1024) cbuf[i] = pts4[b * N + i];
    __syncthreads();

    float4 Q = cbuf[q];
    double k = 1e300;     // lanes 0..15: sorted ascending top-16 keys
    double T = 1e300;     // current 16th-best key (uniform)

#define KNN_INSERT(KEYV)                                              \
    {                                                                 \
        unsigned long long mask = __ballot((KEYV) < T);               \
        while (mask) {                                                \
            int src = __ffsll(mask) - 1;                              \
            mask &= mask - 1;                                         \
            double vb = __shfl((KEYV), src);                          \
            if (vb < T) {                                             \
                double km1 = __shfl_up(k, 1);                         \
                if (lane == 0) km1 = -1.0;                            \
                double kn = (vb <= km1) ? km1 : ((vb < k) ? vb : k);  \
                if (lane < 16) k = kn;                                \
                T = __shfl(k, 15);                                    \
            }                                                         \
        }                                                             \
    }

    for (int c0 = 0; c0 < N; c0 += 128) {
        float4 Ca = cbuf[c0 + lane];
        float4 Cb = cbuf[c0 + 64 + lane];
        float dota = Q.x * Ca.x + Q.y * Ca.y + Q.z * Ca.z;
        float dotb = Q.x * Cb.x + Q.y * Cb.y + Q.z * Cb.z;
        float d2a = Q.w + Ca.w - 2.0f * dota;       // same formula as reference
        float d2b = Q.w + Cb.w - 2.0f * dotb;
        unsigned ua = __float_as_uint(d2a);
        unsigned ub = __float_as_uint(d2b);
        ua ^= (unsigned)((int)ua >> 31) | 0x80000000u;  // orderable uint
        ub ^= (unsigned)((int)ub >> 31) | 0x80000000u;
        double keya = (double)ua * 4096.0 + (double)(c0 + lane);
        double keyb = (double)ub * 4096.0 + (double)(c0 + 64 + lane);
        KNN_INSERT(keya);
        KNN_INSERT(keyb);
    }
#undef KNN_INSERT

    if (lane < 16) {
        long long kl = (long long)k;                 // exact (key < 2^44)
        idxOut[(b * N + q) * 16 + lane] = (int)(kl & 4095);
    }
}

// ---------------- edge features + input LNA + mean over K -> Ytr bf16 hi/lo ----------------
__global__ __launch_bounds__(256) void edge_kernel(const float4* __restrict__ pts4,
                                                   const int* __restrict__ idx,
                                                   const float* __restrict__ Win,
                                                   const float* __restrict__ Uin,
                                                   unsigned short* __restrict__ Yh,
                                                   unsigned short* __restrict__ Yl,
                                                   int N) {
    __shared__ float4 nbuf[8][16];
    __shared__ float4 cpt[8];
    int nTiles = N / 8;
    int b = blockIdx.x / nTiles;
    int n0 = (blockIdx.x % nTiles) * 8;
    int t = threadIdx.x;
    if (t < 128) {
        int pl = t >> 4, k = t & 15;
        int nb = idx[(b * N + n0 + pl) * 16 + k];
        nbuf[pl][k] = pts4[b * N + nb];
    } else if (t < 136) {
        cpt[t - 128] = pts4[b * N + n0 + (t - 128)];
    }
    __syncthreads();
    int o = t & 127, h = t >> 7;
    float w0 = Win[o * 3], w1 = Win[o * 3 + 1], w2 = Win[o * 3 + 2];
    float u0 = Uin[o * 3], u1 = Uin[o * 3 + 1], u2 = Uin[o * 3 + 2];
    for (int pl = h * 4; pl < h * 4 + 4; ++pl) {
        float4 c4 = cpt[pl];
        float inv = 1.0f / fmaxf(sqrtf(c4.w), 1e-12f);
        float ax = c4.x * inv, ay = c4.y * inv, az = c4.z * inv;
        float a0 = 0.f, a1 = 0.f, a2 = 0.f;
        for (int k = 0; k < 16; ++k) {
            float4 nb = nbuf[pl][k];
            float cr0 = ay * nb.z - az * nb.y;
            float cr1 = az * nb.x - ax * nb.z;
            float cr2 = ax * nb.y - ay * nb.x;
            float df0 = nb.x - c4.x, df1 = nb.y - c4.y, df2 = nb.z - c4.z;
            float P0 = w0 * cr0 + w1 * df0 + w2 * c4.x;
            float P1 = w0 * cr1 + w1 * df1 + w2 * c4.y;
            float P2 = w0 * cr2 + w1 * df2 + w2 * c4.z;
            float D0 = u0 * cr0 + u1 * df0 + u2 * c4.x;
            float D1 = u0 * cr1 + u1 * df1 + u2 * c4.y;
            float D2 = u0 * cr2 + u1 * df2 + u2 * c4.z;
            float dot = P0 * D0 + P1 * D1 + P2 * D2;
            float dsq = D0 * D0 + D1 * D1 + D2 * D2;
            if (dot < 0.0f) {
                float s = dot / (dsq + 1e-6f);
                P0 -= s * D0; P1 -= s * D1; P2 -= s * D2;
            }
            a0 += P0; a1 += P1; a2 += P2;
        }
        float vals[3] = { a0 * (1.0f / 16.0f), a1 * (1.0f / 16.0f), a2 * (1.0f / 16.0f) };
        long n = n0 + pl;
#pragma unroll
        for (int c = 0; c < 3; ++c) {
            long off = ((long)(b * 3 + c) * 4096 + n) * 128 + o;
            unsigned short hh = f2bf(vals[c]);
            Yh[off] = hh;
            Yl[off] = f2bf(vals[c] - bf2f(hh));
        }
    }
}

// ---------------- weight pack: per-lane MFMA fragment order, hi/lo ----------------
__global__ __launch_bounds__(256) void pack_kernel(const float* __restrict__ Wl,
                                                   const float* __restrict__ Ul,
                                                   const float* __restrict__ Wg,
                                                   const float* __restrict__ Ug,
                                                   const float* __restrict__ Wout,
                                                   unsigned short* __restrict__ Ah,
                                                   unsigned short* __restrict__ Al) {
    int t = blockIdx.x * 256 + threadIdx.x;     // 0..327679
    int g, r, M; long base;
    if (t < 262144) { g = t >> 15; r = t & 32767; M = 256; base = (long)g << 15; }
    else { int t2 = t - 262144; g = 8 + (t2 >> 14); r = t2 & 16383; M = 128;
           base = 262144 + (long)(g - 8) * 16384; }
    int MF = M >> 4;
    int ks = r / (MF * 512);
    int mf = (r >> 9) % MF;
    int lane = (r >> 3) & 63;
    int j = r & 7;
    int m = mf * 16 + (lane & 15);
    int k = ks * 32 + ((lane >> 4) << 3) + j;
    const float* src; int ldw; int row;
    if (g < 4) {
        ldw = 128; row = m & 127;
        src = (m < 128) ? (Wl + (long)g * 128 * 128) : (Ul + (long)g * 128 * 128);
    } else if (g < 8) {
        ldw = 256; row = m & 127;
        int l = g - 4;
        src = (m < 128) ? (Wg + (long)l * 128 * 256) : (Ug + (long)l * 128 * 256);
    } else {
        ldw = 512; row = m;
        src = Wout + (g - 8) * 128;
    }
    float v = src[(long)row * ldw + k];
    unsigned short h = f2bf(v);
    Ah[base + r] = h;
    Al[base + r] = f2bf(v - bf2f(h));
}

// ---------------- MFMA GEMM, bf16x3, fragments direct from global ----------------
// MODE 0: LNA, no bias; emits per-16col-tile yg partials (shfl_xor col-reduce).
// MODE 1: LNA + bias + fused Wout GEMM (y2 staged in LDS, partial -> Ofp).
// Grid: 256 blocks (b*128 + tile), 512 threads (8 waves: mg = w>>1, ng = w&1).
template<int MODE>
__global__ __launch_bounds__(512, 1) void gemm_kernel(
    const unsigned short* __restrict__ Aph, const unsigned short* __restrict__ Apl,
    long aOff, long aOffOut,
    const unsigned short* __restrict__ Bh, const unsigned short* __restrict__ Bl,
    const float* __restrict__ biasP, const float* __restrict__ biasD,
    unsigned short* __restrict__ Oh, unsigned short* __restrict__ Ol,
    float* __restrict__ Ofp, float* __restrict__ part, int accum)
{
    const int N = 4096;
    // y2 staging for fused Wout: [ng][c][hi/lo][ ((k>>3)*16 + col)*8 + (k&7) ]
    __shared__ unsigned short ylds[MODE == 1 ? 2 : 1][3][2][2048];
    int t = threadIdx.x;
    int lane = t & 63, w = t >> 6;
    int mg = w >> 1, ng = w & 1;
    int b = blockIdx.x >> 7;
    int tile = blockIdx.x & 127;
    int n0 = tile * 32 + ng * 16;
    int ncol = n0 + (lane & 15);
    int kq = (lane >> 4) << 3;

    f32x4 accP[2][3] = {};
    f32x4 accD[2][3] = {};

    const unsigned short* AhB = Aph + aOff;
    const unsigned short* AlB = Apl + aOff;

#pragma unroll
    for (int ks = 0; ks < 4; ++ks) {
        short8 bh[3], bl[3];
#pragma unroll
        for (int c = 0; c < 3; ++c) {
            long boff = ((long)(b * 3 + c) * N + ncol) * 128 + ks * 32 + kq;
            bh[c] = *(const short8*)(Bh + boff);
            bl[c] = *(const short8*)(Bl + boff);
        }
#pragma unroll
        for (int pi = 0; pi < 2; ++pi) {
            int mf = 2 * mg + pi;
            long aoffP = (((long)ks * 16 + mf) * 64 + lane) * 8;
            short8 ahP = *(const short8*)(AhB + aoffP);
            short8 alP = *(const short8*)(AlB + aoffP);
#pragma unroll
            for (int c = 0; c < 3; ++c) {
                accP[pi][c] = __builtin_amdgcn_mfma_f32_16x16x32_bf16(ahP, bh[c], accP[pi][c], 0, 0, 0);
                accP[pi][c] = __builtin_amdgcn_mfma_f32_16x16x32_bf16(ahP, bl[c], accP[pi][c], 0, 0, 0);
                accP[pi][c] = __builtin_amdgcn_mfma_f32_16x16x32_bf16(alP, bh[c], accP[pi][c], 0, 0, 0);
            }
            long aoffD = (((long)ks * 16 + (8 + mf)) * 64 + lane) * 8;
            short8 ahD = *(const short8*)(AhB + aoffD);
            short8 alD = *(const short8*)(AlB + aoffD);
#pragma unroll
            for (int c = 0; c < 3; ++c) {
                accD[pi][c] = __builtin_amdgcn_mfma_f32_16x16x32_bf16(ahD, bh[c], accD[pi][c], 0, 0, 0);
                accD[pi][c] = __builtin_amdgcn_mfma_f32_16x16x32_bf16(ahD, bl[c], accD[pi][c], 0, 0, 0);
                accD[pi][c] = __builtin_amdgcn_mfma_f32_16x16x32_bf16(alD, bh[c], accD[pi][c], 0, 0, 0);
            }
        }
    }

#pragma unroll
    for (int pi = 0; pi < 2; ++pi) {
        int obase = 32 * mg + 16 * pi + ((lane >> 4) << 2);
        float Pv[3][4];
#pragma unroll
        for (int r = 0; r < 4; ++r) {
            int o = obase + r;
            float P[3], D[3];
#pragma unroll
            for (int c = 0; c < 3; ++c) {
                P[c] = accP[pi][c][r];
                D[c] = accD[pi][c][r];
                if (MODE == 1) {
                    long bb = ((long)(b * 128 + o)) * 3 + c;
                    P[c] += biasP[bb];
                    D[c] += biasD[bb];
                }
            }
            float dot = P[0] * D[0] + P[1] * D[1] + P[2] * D[2];
            float dsq = D[0] * D[0] + D[1] * D[1] + D[2] * D[2];
            if (dot < 0.0f) {
                float s = dot / (dsq + 1e-6f);
                P[0] -= s * D[0]; P[1] -= s * D[1]; P[2] -= s * D[2];
            }
            Pv[0][r] = P[0]; Pv[1][r] = P[1]; Pv[2][r] = P[2];
        }
#pragma unroll
        for (int c = 0; c < 3; ++c) {
            unsigned short hs[4], ls[4];
#pragma unroll
            for (int r = 0; r < 4; ++r) {
                hs[r] = f2bf(Pv[c][r]);
                ls[r] = f2bf(Pv[c][r] - bf2f(hs[r]));
            }
            long ooff = ((long)(b * 3 + c) * N + ncol) * 128 + obase;
            *(ushort4*)(Oh + ooff) = make_ushort4(hs[0], hs[1], hs[2], hs[3]);
            *(ushort4*)(Ol + ooff) = make_ushort4(ls[0], ls[1], ls[2], ls[3]);
            if (MODE == 1) {
                int li = ((obase >> 3) << 7) + ((lane & 15) << 3) + (obase & 7);
                *(ushort4*)&ylds[ng][c][0][li] = make_ushort4(hs[0], hs[1], hs[2], hs[3]);
                *(ushort4*)&ylds[ng][c][1][li] = make_ushort4(ls[0], ls[1], ls[2], ls[3]);
            }
        }
        if (MODE == 0) {
            // yg partials: sum over this wave's 16 columns; segment = tile*2+ng.
#pragma unroll
            for (int c = 0; c < 3; ++c) {
#pragma unroll
                for (int r = 0; r < 4; ++r) {
                    float v = Pv[c][r];
                    v += __shfl_xor(v, 1);
                    v += __shfl_xor(v, 2);
                    v += __shfl_xor(v, 4);
                    v += __shfl_xor(v, 8);
                    if ((lane & 15) == 0)
                        part[((long)(b * 3 + c) * 256 + tile * 2 + ng) * 128 + (obase + r)] = v;
                }
            }
        }
    }

    if (MODE == 1) {
        __syncthreads();
        f32x4 accO[2][3] = {};
        const unsigned short* AoH = Aph + aOffOut;
        const unsigned short* AoL = Apl + aOffOut;
#pragma unroll
        for (int ks = 0; ks < 4; ++ks) {
            short8 yh[3], yl[3];
            int li = (((ks << 2) + (lane >> 4)) << 7) + ((lane & 15) << 3);
#pragma unroll
            for (int c = 0; c < 3; ++c) {
                yh[c] = *(const short8*)&ylds[ng][c][0][li];
                yl[c] = *(const short8*)&ylds[ng][c][1][li];
            }
#pragma unroll
            for (int pi = 0; pi < 2; ++pi) {
                int mf = 2 * mg + pi;
                long aoff = (((long)ks * 8 + mf) * 64 + lane) * 8;
                short8 ah = *(const short8*)(AoH + aoff);
                short8 al = *(const short8*)(AoL + aoff);
#pragma unroll
                for (int c = 0; c < 3; ++c) {
                    accO[pi][c] = __builtin_amdgcn_mfma_f32_16x16x32_bf16(ah, yh[c], accO[pi][c], 0, 0, 0);
                    accO[pi][c] = __builtin_amdgcn_mfma_f32_16x16x32_bf16(ah, yl[c], accO[pi][c], 0, 0, 0);
                    accO[pi][c] = __builtin_amdgcn_mfma_f32_16x16x32_bf16(al, yh[c], accO[pi][c], 0, 0, 0);
                }
            }
        }
#pragma unroll
        for (int pi = 0; pi < 2; ++pi) {
            int obase = 32 * mg + 16 * pi + ((lane >> 4) << 2);
#pragma unroll
            for (int r = 0; r < 4; ++r) {
                int o = obase + r;
#pragma unroll
                for (int c = 0; c < 3; ++c) {
                    long off = ((long)(b * 128 + o) * 3 + c) * N + ncol;
                    float v = accO[pi][c][r];
                    if (accum) v += Ofp[off];
                    Ofp[off] = v;
                }
            }
        }
    }
}

// ---------------- yg stage2 + bias, single block ----------------
// part: [bc][seg 0..255][o 0..127]; bias layout t = (b*128+o)*3+c.
__global__ __launch_bounds__(768) void ygbias_kernel(const float* __restrict__ part,
                                                     const float* __restrict__ Wg,
                                                     const float* __restrict__ Ug,
                                                     float* __restrict__ biasP,
                                                     float* __restrict__ biasD) {
    __shared__ float ygl[768];    // [(b*128+i)*3+c]
    int t = threadIdx.x;          // 0..767
    int bc = t >> 7, o = t & 127;
    float s = 0.f;
    for (int seg = 0; seg < 256; ++seg)
        s += part[((long)bc * 256 + seg) * 128 + o];
    int b = bc / 3, c = bc % 3;
    ygl[(b * 128 + o) * 3 + c] = s * (1.0f / 4096.0f);
    __syncthreads();
    int c2 = t % 3, o2 = (t / 3) % 128, b2 = t / 384;
    float sp = 0.f, sd = 0.f;
    const float* wrow = Wg + o2 * 256 + 128;
    const float* urow = Ug + o2 * 256 + 128;
    for (int i = 0; i < 128; ++i) {
        float y = ygl[(b2 * 128 + i) * 3 + c2];
        sp = fmaf(wrow[i], y, sp);
        sd = fmaf(urow[i], y, sd);
    }
    biasP[t] = sp;
    biasD[t] = sd;
}

// ---------------- mean over N per (b, o, c) row of fp32 out1 ----------------
__global__ __launch_bounds__(256) void reduce_mean_kernel(const float* __restrict__ src, long bs,
                                                          float* __restrict__ dst, int N) {
    __shared__ float red[256];
    int row = blockIdx.x;          // (b*128+o)*3 + c
    int b = row / 384; int rr = row % 384;
    const float* p = src + (long)b * bs + (long)rr * N;
    float s = 0.f;
    for (int i = threadIdx.x; i < N; i += 256) s += p[i];
    red[threadIdx.x] = s;
    __syncthreads();
    for (int st = 128; st > 0; st >>= 1) {
        if (threadIdx.x < st) red[threadIdx.x] += red[threadIdx.x + st];
        __syncthreads();
    }
    if (threadIdx.x == 0) dst[row] = red[0] / (float)N;
}

extern "C" void kernel_launch(void* const* d_in, const int* in_sizes, int n_in,
                              void* d_out, int out_size, void* d_ws, size_t ws_size,
                              hipStream_t stream) {
    const float* x    = (const float*)d_in[0];
    const float* Win  = (const float*)d_in[1];
    const float* Uin  = (const float*)d_in[2];
    const float* Wl   = (const float*)d_in[3];
    const float* Ul   = (const float*)d_in[4];
    const float* Wg   = (const float*)d_in[5];
    const float* Ug   = (const float*)d_in[6];
    const float* Wout = (const float*)d_in[7];

    const int B = 2, N = 4096, H = 128;
    float* out0 = (float*)d_out;                 // (B,128,3) mean
    float* out1 = out0 + (long)B * H * 3;        // (B,128,3,N) fp32

    float* ws = (float*)d_ws;
    long off = 0;
    float4* pts4 = (float4*)ws;                  off += (long)B * N * 4;
    int* idx = (int*)(ws + off);                 off += (long)B * N * 16;
    const long ACT = (long)B * 3 * N * H;        // ushort count
    unsigned short* f0h = (unsigned short*)(ws + off);  off += ACT / 2;
    unsigned short* f0l = (unsigned short*)(ws + off);  off += ACT / 2;
    unsigned short* y1h = (unsigned short*)(ws + off);  off += ACT / 2;
    unsigned short* y1l = (unsigned short*)(ws + off);  off += ACT / 2;
    unsigned short* Aph = (unsigned short*)(ws + off);  off += 327680 / 2;
    unsigned short* Apl = (unsigned short*)(ws + off);  off += 327680 / 2;
    float* part  = ws + off;                     off += 6L * 256 * 128;
    float* biasP = ws + off;                     off += B * H * 3;
    float* biasD = ws + off;                     off += B * H * 3;
    // ~27.6 MB of workspace

    long bs128 = (long)H * 3 * N;

    prep_kernel<<<(B * N + 255) / 256, 256, 0, stream>>>(x, pts4, N, B);
    knn_kernel<<<B * (N / 16), 1024, 0, stream>>>(pts4, idx, N);
    edge_kernel<<<B * (N / 8), 256, 0, stream>>>(pts4, idx, Win, Uin, f0h, f0l, N);
    pack_kernel<<<1280, 256, 0, stream>>>(Wl, Ul, Wg, Ug, Wout, Aph, Apl);

    for (int l = 0; l < 4; ++l) {
        // y1 = LNA(Wl y2prev, Ul y2prev); emits per-tile yg partials
        gemm_kernel<0><<<256, 512, 0, stream>>>(
            Aph, Apl, (long)l * 32768, 0, f0h, f0l, nullptr, nullptr,
            y1h, y1l, nullptr, part, 0);
        // yg = mean(part); bias = Wg[:,128:] @ yg (and Ug)
        ygbias_kernel<<<1, 768, 0, stream>>>(part,
            Wg + (long)l * H * 256, Ug + (long)l * H * 256, biasP, biasD);
        // y2 = LNA(Wg y1 + biasP, Ug y1 + biasD) -> f0 ; out1 (+)= Wout_l @ y2 (fused)
        gemm_kernel<1><<<256, 512, 0, stream>>>(
            Aph, Apl, (long)(4 + l) * 32768, 262144 + (long)l * 16384,
            y1h, y1l, biasP, biasD, f0h, f0l, out1, nullptr, l > 0 ? 1 : 0);
    }
    reduce_mean_kernel<<<B * H * 3, 256, 0, stream>>>(out1, bs128, out0, N);
}